// Round 3
// baseline (571.243 us; speedup 1.0000x reference)
//
#include <hip/hip_runtime.h>

// Router_26817775796684 — MI355X/gfx950, round 5.
// conv3x3(SAME)+relu+meanpool+fc+softmax+adaptive-threshold+sigmoid-renorm, fused.
//
// Round-5 change (vs round 4): eliminate the residual K-loop spill.
// Round 4 fit acc[4][4] into 64 AGPRs but the 64-VGPR half couldn't hold
// bcur+bnext+afr+addressing (57 MB scratch writes, MfmaUtil 26%). The B
// double-buffer (16 VGPRs) is unnecessary at 4 waves/SIMD — TLP covers the
// ~200cy L2-hit latency (each SIMD has ~1240cy of MFMA work per chunk).
// Single-buffered B, loaded at the top of each unrolled chunk; live set
// now ~120 unified regs -> zero spill at the (256,4) cap of 128.

typedef _Float16 half8 __attribute__((ext_vector_type(8)));
typedef float    floatx4 __attribute__((ext_vector_type(4)));

#define A_SAMPLE  14400              // 100 rows * 144 B
#define LDS_P_OFF 28800              // pooled[2][128] fp32 after 2 A samples
#define LDS_TOTAL 29824

__global__ void prep_weights(const float* __restrict__ cw, _Float16* __restrict__ Bw) {
  int i = blockIdx.x * 256 + threadIdx.x;   // 0 .. 128*672-1
  int co = i / 672;
  int k  = i - co * 672;
  int s  = k / 72;                          // shift index (9 real, 9 = tail pad)
  int ci = k - s * 72;
  float v = 0.f;
  if (s < 9 && ci < 68) {
    int ky = s / 3, kx = s - 3 * ky;
    v = cw[((co * 68 + ci) * 3 + ky) * 3 + kx];
  }
  Bw[i] = (_Float16)v;                      // pads are EXACT zeros (never NaN)
}

__global__ __launch_bounds__(256, 4) void router_main(
    const float* __restrict__ patch,
    const float* __restrict__ conv_b,
    const _Float16* __restrict__ Bw,
    const float* __restrict__ fc_w,
    const float* __restrict__ fc_b,
    const float* __restrict__ p_wmax,
    const float* __restrict__ p_went,
    const float* __restrict__ p_wgap,
    const float* __restrict__ p_thr,
    const int* __restrict__ p_epoch,
    float* __restrict__ out)
{
  __shared__ __align__(16) unsigned char lds[LDS_TOTAL];
  const int tid    = threadIdx.x;
  const int l      = tid & 63;
  const int w      = tid >> 6;      // wave 0..3
  const int lane15 = l & 15;
  const int quad   = l >> 4;
  const int sm     = w >> 1;        // sample within WG (0,1)
  const int h      = w & 1;         // N-half AND staging-half
  const int n0     = h * 64;
  const int n_s    = blockIdx.x * 2;

  // ---- zero-fill BORDER rows only (36 rows * 9 slots = 324 b128/sample),
  //      split by h. Interior rows are fully covered by staged block writes,
  //      so no cross-wave write-ordering is needed (all addresses disjoint).
  {
    unsigned char* abase = lds + sm * A_SAMPLE;
    float4 z4 = make_float4(0.f, 0.f, 0.f, 0.f);
    #pragma unroll
    for (int j0 = 0; j0 < 3; ++j0) {
      int jj = j0 * 64 + l;
      if (jj < 162) {
        int j   = h * 162 + jj;               // 0..323
        int ri  = j / 9;                      // border-row index 0..35
        int col = j - ri * 9;
        // ri 0..9 -> rows 0..9; ri 10..25 -> rows 10,19,20,29,...,80,89;
        // ri 26..35 -> rows 90..99
        int row = (ri < 10) ? ri
                : (ri < 26) ? ((((ri - 10) >> 1) + 1) * 10 + ((ri - 10) & 1) * 9)
                            : (ri + 64);
        *(float4*)(abase + row * 144 + col * 16) = z4;
      }
    }
  }
  // ---- stage interior: lane l = position p=(y,x) -> padded row (y+1)*10+(x+1).
  //      Wave h stages ci-blocks b = 2*bb + h (even/odd split, disjoint 16B slots).
  {
    const float* psrc = patch + (size_t)(n_s + sm) * 4352 + l;   // [ci][p] layout
    int y = l >> 3, x = l & 7;
    unsigned char* arow = lds + sm * A_SAMPLE + ((y + 1) * 10 + (x + 1)) * 144;
    #pragma unroll
    for (int bb = 0; bb < 5; ++bb) {
      int b = bb * 2 + h;                     // h=0: 0,2,4,6,8  h=1: 1,3,5,7,(9 skipped)
      if (b < 9) {
        half8 hh;
        #pragma unroll
        for (int j = 0; j < 8; ++j) {
          int ci = b * 8 + j;
          float v = (ci < 68) ? psrc[ci * 64] : 0.f;   // 256 B/instr coalesced
          hh[j] = (_Float16)v;
        }
        *(half8*)(arow + b * 16) = hh;
      }
    }
  }
  __syncthreads();

  // ---- loop-invariant A fragment base offsets (this wave's 4 M-tiles) ----
  int apos[4];
  #pragma unroll
  for (int t = 0; t < 4; ++t) {
    int p  = t * 16 + lane15;                             // position within sample
    int pp = ((p >> 3) + 1) * 10 + (p & 7) + 1;           // padded row
    apos[t] = sm * A_SAMPLE + pp * 144;
  }

  // ---- B gather pointers (per-lane; 172 KB table is L2-resident) ----
  const _Float16* bptr[4];
  #pragma unroll
  for (int n = 0; n < 4; ++n)
    bptr[n] = Bw + (size_t)(n0 + n * 16 + lane15) * 672 + quad * 8;

  floatx4 acc[4][4];
  floatx4 zacc = {0.f, 0.f, 0.f, 0.f};
  #pragma unroll
  for (int t = 0; t < 4; ++t)
    #pragma unroll
    for (int n = 0; n < 4; ++n) acc[t][n] = zacc;

  // ---- barrier-free K loop: 20 full chunks (kb = 4c+quad <= 79, all valid).
  //      Single-buffered B: loads issue at chunk top; unroll-4 window lets the
  //      scheduler hoist next-chunk loads under current-chunk MFMAs. ----
  #pragma unroll 4
  for (int c = 0; c < 20; ++c) {
    half8 bfr[4];
    #pragma unroll
    for (int n = 0; n < 4; ++n)
      bfr[n] = *(const half8*)(bptr[n] + c * 32);        // const offset folds

    int kb  = c * 4 + quad;
    int s   = (kb * 57) >> 9;           // kb/9, exact for 0..83
    int rem = kb - s * 9;
    int dy  = (s * 11) >> 5;            // s/3
    int dx  = s - 3 * dy;
    int roff = (dy * 10 + dx - 11) * 144 + rem * 16;       // affine shift offset

    half8 afr[4];
    #pragma unroll
    for (int t = 0; t < 4; ++t)
      afr[t] = *(const half8*)(lds + apos[t] + roff);

    #pragma unroll
    for (int t = 0; t < 4; ++t)
      #pragma unroll
      for (int n = 0; n < 4; ++n)
        acc[t][n] = __builtin_amdgcn_mfma_f32_16x16x32_f16(afr[t], bfr[n], acc[t][n], 0, 0, 0);
  }

  // ---- peeled tail chunk c=20: kb=80 (quad 0) real; kb 81..83 are zero B columns,
  //      so A contents are irrelevant — clamp offset in-bounds (finite data). ----
  {
    half8 bfr[4];
    #pragma unroll
    for (int n = 0; n < 4; ++n)
      bfr[n] = *(const half8*)(bptr[n] + 20 * 32);
    int roff = (quad == 0) ? 1712 : 0;  // kb=80: s=8,rem=8 -> (20+2-11)*144+128
    half8 afr[4];
    #pragma unroll
    for (int t = 0; t < 4; ++t)
      afr[t] = *(const half8*)(lds + apos[t] + roff);
    #pragma unroll
    for (int t = 0; t < 4; ++t)
      #pragma unroll
      for (int n = 0; n < 4; ++n)
        acc[t][n] = __builtin_amdgcn_mfma_f32_16x16x32_f16(afr[t], bfr[n], acc[t][n], 0, 0, 0);
  }

  // ---- bias + relu + mean-pool (C layout: row = quad*4+reg, col = lane15) ----
  float bcoef[4];
  #pragma unroll
  for (int n = 0; n < 4; ++n) bcoef[n] = conv_b[n0 + n * 16 + lane15];

  float* pl = (float*)(lds + LDS_P_OFF);          // pooled[2][128]
  #pragma unroll
  for (int n = 0; n < 4; ++n) {
    float ssum = 0.f;
    #pragma unroll
    for (int t = 0; t < 4; ++t)
      #pragma unroll
      for (int r = 0; r < 4; ++r)
        ssum += fmaxf(acc[t][n][r] + bcoef[n], 0.f);
    ssum += __shfl_xor(ssum, 16);                 // sum the 4 quad partials
    ssum += __shfl_xor(ssum, 32);
    if (l < 16)
      pl[sm * 128 + n0 + n * 16 + lane15] = ssum * (1.f / 64.f);
  }
  __syncthreads();

  // ---- fused routing epilogue: wave w (w<2) handles sample (n_s + w) ----
  if (w < 2) {
    const float* plw = pl + w * 128;
    int e  = l >> 3;                               // expert 0..7
    int c8 = l & 7;
    float part = 0.f;
    #pragma unroll
    for (int m = 0; m < 16; ++m) {
      int co = c8 + 8 * m;
      part += plw[co] * fc_w[co * 8 + e];
    }
    part += __shfl_xor(part, 1);
    part += __shfl_xor(part, 2);
    part += __shfl_xor(part, 4);

    float lg[8];
    #pragma unroll
    for (int j = 0; j < 8; ++j) lg[j] = __shfl(part, j * 8) + fc_b[j];

    float mx = lg[0];
    #pragma unroll
    for (int j = 1; j < 8; ++j) mx = fmaxf(mx, lg[j]);
    float wgt[8]; float sum = 0.f;
    #pragma unroll
    for (int j = 0; j < 8; ++j) { wgt[j] = expf(lg[j] - mx); sum += wgt[j]; }
    float inv = 1.f / sum;
    #pragma unroll
    for (int j = 0; j < 8; ++j) wgt[j] *= inv;

    // sort descending — Batcher odd-even, 19 comparators
    float sw[8];
    #pragma unroll
    for (int j = 0; j < 8; ++j) sw[j] = wgt[j];
    #define CSD(i, j) { float hi_ = fmaxf(sw[i], sw[j]); float lo_ = fminf(sw[i], sw[j]); sw[i] = hi_; sw[j] = lo_; }
    CSD(0,1) CSD(2,3) CSD(4,5) CSD(6,7)
    CSD(0,2) CSD(1,3) CSD(4,6) CSD(5,7)
    CSD(1,2) CSD(5,6)
    CSD(0,4) CSD(1,5) CSD(2,6) CSD(3,7)
    CSD(2,4) CSD(3,5)
    CSD(1,2) CSD(3,4) CSD(5,6)
    #undef CSD

    float s1 = 0.f;
    #pragma unroll
    for (int j = 0; j < 8; ++j) s1 += wgt[j];
    float mean = s1 * 0.125f;
    float var = 0.f;
    #pragma unroll
    for (int j = 0; j < 8; ++j) { float d = wgt[j] - mean; var += d * d; }
    float stdv = sqrtf(var * (1.f / 7.f));          // ddof=1
    float ent = 0.f;
    #pragma unroll
    for (int j = 0; j < 8; ++j) ent -= wgt[j] * logf(wgt[j] + 1e-18f);

    float maxc  = 1.f - sw[0];
    float entc  = 1.f - ent * 0.48089834696298783f; // 1/log(8)
    float mrest = (sw[1] + sw[2] + sw[3] + sw[4]) * 0.25f;
    float gap   = (sw[0] - mrest) / (sw[0] + 1e-8f);
    gap = fminf(fmaxf(gap, 0.f), 1.f);
    float af = p_wmax[0] * maxc + p_went[0] * entc + p_wgap[0] * gap;
    float th = p_thr[0] * (0.5f + af);
    float mn  = fmaxf(0.05f, mean - 0.5f * stdv);
    float mxt = fminf(0.7f, sw[0] - 0.1f * stdv);
    th = fminf(fmaxf(th, mn), mxt);                 // jnp.clip: lower then upper
    th = fminf(th, sw[1] * 0.9f);                   // kth = sw[MIN_EXPERTS_ACTIVE-1]

    int epoch = p_epoch[0];
    float outv[8];
    if (epoch < 20) {
      #pragma unroll
      for (int j = 0; j < 8; ++j) outv[j] = 0.125f;
    } else {
      float tau = (epoch <= 25) ? fmaxf(0.1f, 1.0f - (float)(epoch - 20) * 0.18f) : 0.1f;
      // forward value of hard + stopgrad(soft-hard) == soft exactly
      float ssum = 0.f;
      #pragma unroll
      for (int j = 0; j < 8; ++j) {
        float sj = 1.f / (1.f + expf(-(wgt[j] - th) / tau));
        outv[j] = sj; ssum += sj;
      }
      float invs = 1.f / fmaxf(ssum, 1e-8f);
      #pragma unroll
      for (int j = 0; j < 8; ++j) outv[j] *= invs;
    }

    if (l < 8) {
      float mv = outv[0];
      #pragma unroll
      for (int j = 1; j < 8; ++j) mv = (l == j) ? outv[j] : mv;
      out[(n_s + w) * 8 + l] = mv;
    }
  }
}

extern "C" void kernel_launch(void* const* d_in, const int* in_sizes, int n_in,
                              void* d_out, int out_size, void* d_ws, size_t ws_size,
                              hipStream_t stream) {
  const float* patch  = (const float*)d_in[0];
  const float* conv_w = (const float*)d_in[1];
  const float* conv_b = (const float*)d_in[2];
  const float* fc_w   = (const float*)d_in[3];
  const float* fc_b   = (const float*)d_in[4];
  const float* wmax   = (const float*)d_in[5];
  const float* went   = (const float*)d_in[6];
  const float* wgap   = (const float*)d_in[7];
  const float* thr    = (const float*)d_in[8];
  const int*   epoch  = (const int*)d_in[10];
  float* outp = (float*)d_out;
  _Float16* Bw = (_Float16*)d_ws;                 // 128*672*2 = 172,032 B of ws

  int N = in_sizes[0] / 4352;                     // 16384 samples
  prep_weights<<<336, 256, 0, stream>>>(conv_w, Bw);
  router_main<<<N / 2, 256, 0, stream>>>(patch, conv_b, Bw, fc_w, fc_b,
                                         wmax, went, wgap, thr, epoch, outp);
}

// Round 4
// 536.928 us; speedup vs baseline: 1.0639x; 1.0639x over previous
//
#include <hip/hip_runtime.h>

// Router_26817775796684 — MI355X/gfx950, round 6.
// conv3x3(SAME)+relu+meanpool+fc+softmax+adaptive-threshold+sigmoid-renorm, fused.
//
// Round-6 changes (vs round 5): kill the L2 roofline AND the spill together.
//   * Rounds 4/5 were L2-BW-bound: B loads had lane-stride 1344 B -> 64
//     distinct cache lines per instruction -> 11.3 GB of L2 traffic =
//     ~36 TB/s at 310 us (the L2 ceiling). B is now REPACKED by prep_weights
//     into per-lane read order [h][chunk][lane][frag]: 4 coalesced 1-KB
//     global_load_dwordx4 per chunk (2.75 GB L2 traffic total).
//   * Repack collapses bptr[4] (8 regs) to one base; explicit one-chunk
//     B double-buffer under '#pragma unroll 1': live set ~126 unified regs
//     (64 AGPR acc + ~62 VGPR) -> fits the (256,4) cap of 128, no scratch.
//   * Tail chunk c=20 needs no special B handling: prep stores exact zeros
//     for kb 81..83 (kdim >= 648 -> s == 9 -> padded zero).

typedef _Float16 half8 __attribute__((ext_vector_type(8)));
typedef float    floatx4 __attribute__((ext_vector_type(4)));

#define A_SAMPLE  14400              // 100 rows * 144 B
#define LDS_P_OFF 28800              // pooled[2][128] fp32 after 2 A samples
#define LDS_TOTAL 29824

// Repacked B: half-element index i = h*43008 + c*2048 + l*32 + n*8 + j
//   (21 chunks * 4096 B per (h,c); 64 B per lane; 16 B per fragment)
__global__ void prep_weights(const float* __restrict__ cw, _Float16* __restrict__ Bw) {
  int i  = blockIdx.x * 256 + threadIdx.x;   // 0..86015 (half elements)
  int h  = (i >= 43008) ? 1 : 0;
  int r1 = i - h * 43008;
  int c  = r1 >> 11;                         // chunk 0..20
  int r2 = r1 & 2047;
  int l  = r2 >> 5;                          // lane 0..63
  int r3 = r2 & 31;
  int n  = r3 >> 3;                          // fragment 0..3
  int j  = r3 & 7;
  int quad = l >> 4, lane15 = l & 15;
  int col  = h * 64 + n * 16 + lane15;       // output channel 0..127
  int kdim = (c * 4 + quad) * 8 + j;         // K index 0..671
  int kb   = kdim >> 3;
  int s    = (kb * 57) >> 9;                 // kb/9, exact for 0..83
  int ci   = kdim - s * 72;
  float v = 0.f;
  if (s < 9 && ci < 68) {
    int ky = s / 3, kx = s - 3 * ky;
    v = cw[((col * 68 + ci) * 3 + ky) * 3 + kx];
  }
  Bw[i] = (_Float16)v;                       // pads are EXACT zeros (never NaN)
}

__global__ __launch_bounds__(256, 4) void router_main(
    const float* __restrict__ patch,
    const float* __restrict__ conv_b,
    const _Float16* __restrict__ Bw,
    const float* __restrict__ fc_w,
    const float* __restrict__ fc_b,
    const float* __restrict__ p_wmax,
    const float* __restrict__ p_went,
    const float* __restrict__ p_wgap,
    const float* __restrict__ p_thr,
    const int* __restrict__ p_epoch,
    float* __restrict__ out)
{
  __shared__ __align__(16) unsigned char lds[LDS_TOTAL];
  const int tid    = threadIdx.x;
  const int l      = tid & 63;
  const int w      = tid >> 6;      // wave 0..3
  const int lane15 = l & 15;
  const int quad   = l >> 4;
  const int sm     = w >> 1;        // sample within WG (0,1)
  const int h      = w & 1;         // N-half AND staging-half
  const int n0     = h * 64;
  const int n_s    = blockIdx.x * 2;

  // ---- zero-fill BORDER rows only (36 rows * 9 slots = 324 b128/sample),
  //      split by h. Interior rows are fully covered by staged block writes,
  //      so no cross-wave write-ordering is needed (all addresses disjoint).
  {
    unsigned char* abase = lds + sm * A_SAMPLE;
    float4 z4 = make_float4(0.f, 0.f, 0.f, 0.f);
    #pragma unroll
    for (int j0 = 0; j0 < 3; ++j0) {
      int jj = j0 * 64 + l;
      if (jj < 162) {
        int j   = h * 162 + jj;               // 0..323
        int ri  = j / 9;                      // border-row index 0..35
        int col = j - ri * 9;
        // ri 0..9 -> rows 0..9; ri 10..25 -> rows 10,19,20,29,...,80,89;
        // ri 26..35 -> rows 90..99
        int row = (ri < 10) ? ri
                : (ri < 26) ? ((((ri - 10) >> 1) + 1) * 10 + ((ri - 10) & 1) * 9)
                            : (ri + 64);
        *(float4*)(abase + row * 144 + col * 16) = z4;
      }
    }
  }
  // ---- stage interior: lane l = position p=(y,x) -> padded row (y+1)*10+(x+1).
  //      Wave h stages ci-blocks b = 2*bb + h (even/odd split, disjoint 16B slots).
  {
    const float* psrc = patch + (size_t)(n_s + sm) * 4352 + l;   // [ci][p] layout
    int y = l >> 3, x = l & 7;
    unsigned char* arow = lds + sm * A_SAMPLE + ((y + 1) * 10 + (x + 1)) * 144;
    #pragma unroll
    for (int bb = 0; bb < 5; ++bb) {
      int b = bb * 2 + h;                     // h=0: 0,2,4,6,8  h=1: 1,3,5,7,(9 skipped)
      if (b < 9) {
        half8 hh;
        #pragma unroll
        for (int j = 0; j < 8; ++j) {
          int ci = b * 8 + j;
          float v = (ci < 68) ? psrc[ci * 64] : 0.f;   // 256 B/instr coalesced
          hh[j] = (_Float16)v;
        }
        *(half8*)(arow + b * 16) = hh;
      }
    }
  }
  __syncthreads();

  // ---- loop-invariant A fragment base offsets (this wave's 4 M-tiles) ----
  int apos[4];
  #pragma unroll
  for (int t = 0; t < 4; ++t) {
    int p  = t * 16 + lane15;                             // position within sample
    int pp = ((p >> 3) + 1) * 10 + (p & 7) + 1;           // padded row
    apos[t] = sm * A_SAMPLE + pp * 144;
  }

  // ---- per-lane B base (repacked layout: contiguous 64 B per lane-chunk) ----
  const _Float16* bb = Bw + h * 43008 + l * 32;

  floatx4 acc[4][4];
  floatx4 zacc = {0.f, 0.f, 0.f, 0.f};
  #pragma unroll
  for (int t = 0; t < 4; ++t)
    #pragma unroll
    for (int n = 0; n < 4; ++n) acc[t][n] = zacc;

  // preload B chunk 0 (coalesced 1 KB/wave per fragment set)
  half8 bcur[4];
  #pragma unroll
  for (int n = 0; n < 4; ++n) bcur[n] = *(const half8*)(bb + n * 8);

  // ---- barrier-free K loop: 20 full chunks (kb = 4c+quad <= 79, all valid).
  //      One-chunk B double-buffer; unroll 1 keeps the live set at ~126
  //      unified regs (no scratch at the 128 cap). ----
  #pragma unroll 1
  for (int c = 0; c < 20; ++c) {
    half8 bnext[4];
    #pragma unroll
    for (int n = 0; n < 4; ++n)
      bnext[n] = *(const half8*)(bb + (c + 1) * 2048 + n * 8);

    int kb  = c * 4 + quad;
    int s   = (kb * 57) >> 9;           // kb/9, exact for 0..83
    int rem = kb - s * 9;
    int dy  = (s * 11) >> 5;            // s/3
    int dx  = s - 3 * dy;
    int roff = (dy * 10 + dx - 11) * 144 + rem * 16;       // affine shift offset

    half8 afr[4];
    #pragma unroll
    for (int t = 0; t < 4; ++t)
      afr[t] = *(const half8*)(lds + apos[t] + roff);

    #pragma unroll
    for (int t = 0; t < 4; ++t)
      #pragma unroll
      for (int n = 0; n < 4; ++n)
        acc[t][n] = __builtin_amdgcn_mfma_f32_16x16x32_f16(afr[t], bcur[n], acc[t][n], 0, 0, 0);

    #pragma unroll
    for (int n = 0; n < 4; ++n) bcur[n] = bnext[n];
  }

  // ---- tail chunk c=20 (bcur already holds it): kb=80 (quad 0) real;
  //      kb 81..83 have exact-zero B fragments (from prep), so A contents
  //      are irrelevant — clamp offset in-bounds (finite data). ----
  {
    int roff = (quad == 0) ? 1712 : 0;  // kb=80: s=8,rem=8 -> (20+2-11)*144+128
    half8 afr[4];
    #pragma unroll
    for (int t = 0; t < 4; ++t)
      afr[t] = *(const half8*)(lds + apos[t] + roff);
    #pragma unroll
    for (int t = 0; t < 4; ++t)
      #pragma unroll
      for (int n = 0; n < 4; ++n)
        acc[t][n] = __builtin_amdgcn_mfma_f32_16x16x32_f16(afr[t], bcur[n], acc[t][n], 0, 0, 0);
  }

  // ---- bias + relu + mean-pool (C layout: row = quad*4+reg, col = lane15) ----
  float bcoef[4];
  #pragma unroll
  for (int n = 0; n < 4; ++n) bcoef[n] = conv_b[n0 + n * 16 + lane15];

  float* pl = (float*)(lds + LDS_P_OFF);          // pooled[2][128]
  #pragma unroll
  for (int n = 0; n < 4; ++n) {
    float ssum = 0.f;
    #pragma unroll
    for (int t = 0; t < 4; ++t)
      #pragma unroll
      for (int r = 0; r < 4; ++r)
        ssum += fmaxf(acc[t][n][r] + bcoef[n], 0.f);
    ssum += __shfl_xor(ssum, 16);                 // sum the 4 quad partials
    ssum += __shfl_xor(ssum, 32);
    if (l < 16)
      pl[sm * 128 + n0 + n * 16 + lane15] = ssum * (1.f / 64.f);
  }
  __syncthreads();

  // ---- fused routing epilogue: wave w (w<2) handles sample (n_s + w) ----
  if (w < 2) {
    const float* plw = pl + w * 128;
    int e  = l >> 3;                               // expert 0..7
    int c8 = l & 7;
    float part = 0.f;
    #pragma unroll
    for (int m = 0; m < 16; ++m) {
      int co = c8 + 8 * m;
      part += plw[co] * fc_w[co * 8 + e];
    }
    part += __shfl_xor(part, 1);
    part += __shfl_xor(part, 2);
    part += __shfl_xor(part, 4);

    float lg[8];
    #pragma unroll
    for (int j = 0; j < 8; ++j) lg[j] = __shfl(part, j * 8) + fc_b[j];

    float mx = lg[0];
    #pragma unroll
    for (int j = 1; j < 8; ++j) mx = fmaxf(mx, lg[j]);
    float wgt[8]; float sum = 0.f;
    #pragma unroll
    for (int j = 0; j < 8; ++j) { wgt[j] = expf(lg[j] - mx); sum += wgt[j]; }
    float inv = 1.f / sum;
    #pragma unroll
    for (int j = 0; j < 8; ++j) wgt[j] *= inv;

    // sort descending — Batcher odd-even, 19 comparators
    float sw[8];
    #pragma unroll
    for (int j = 0; j < 8; ++j) sw[j] = wgt[j];
    #define CSD(i, j) { float hi_ = fmaxf(sw[i], sw[j]); float lo_ = fminf(sw[i], sw[j]); sw[i] = hi_; sw[j] = lo_; }
    CSD(0,1) CSD(2,3) CSD(4,5) CSD(6,7)
    CSD(0,2) CSD(1,3) CSD(4,6) CSD(5,7)
    CSD(1,2) CSD(5,6)
    CSD(0,4) CSD(1,5) CSD(2,6) CSD(3,7)
    CSD(2,4) CSD(3,5)
    CSD(1,2) CSD(3,4) CSD(5,6)
    #undef CSD

    float s1 = 0.f;
    #pragma unroll
    for (int j = 0; j < 8; ++j) s1 += wgt[j];
    float mean = s1 * 0.125f;
    float var = 0.f;
    #pragma unroll
    for (int j = 0; j < 8; ++j) { float d = wgt[j] - mean; var += d * d; }
    float stdv = sqrtf(var * (1.f / 7.f));          // ddof=1
    float ent = 0.f;
    #pragma unroll
    for (int j = 0; j < 8; ++j) ent -= wgt[j] * logf(wgt[j] + 1e-18f);

    float maxc  = 1.f - sw[0];
    float entc  = 1.f - ent * 0.48089834696298783f; // 1/log(8)
    float mrest = (sw[1] + sw[2] + sw[3] + sw[4]) * 0.25f;
    float gap   = (sw[0] - mrest) / (sw[0] + 1e-8f);
    gap = fminf(fmaxf(gap, 0.f), 1.f);
    float af = p_wmax[0] * maxc + p_went[0] * entc + p_wgap[0] * gap;
    float th = p_thr[0] * (0.5f + af);
    float mn  = fmaxf(0.05f, mean - 0.5f * stdv);
    float mxt = fminf(0.7f, sw[0] - 0.1f * stdv);
    th = fminf(fmaxf(th, mn), mxt);                 // jnp.clip: lower then upper
    th = fminf(th, sw[1] * 0.9f);                   // kth = sw[MIN_EXPERTS_ACTIVE-1]

    int epoch = p_epoch[0];
    float outv[8];
    if (epoch < 20) {
      #pragma unroll
      for (int j = 0; j < 8; ++j) outv[j] = 0.125f;
    } else {
      float tau = (epoch <= 25) ? fmaxf(0.1f, 1.0f - (float)(epoch - 20) * 0.18f) : 0.1f;
      // forward value of hard + stopgrad(soft-hard) == soft exactly
      float ssum = 0.f;
      #pragma unroll
      for (int j = 0; j < 8; ++j) {
        float sj = 1.f / (1.f + expf(-(wgt[j] - th) / tau));
        outv[j] = sj; ssum += sj;
      }
      float invs = 1.f / fmaxf(ssum, 1e-8f);
      #pragma unroll
      for (int j = 0; j < 8; ++j) outv[j] *= invs;
    }

    if (l < 8) {
      float mv = outv[0];
      #pragma unroll
      for (int j = 1; j < 8; ++j) mv = (l == j) ? outv[j] : mv;
      out[(n_s + w) * 8 + l] = mv;
    }
  }
}

extern "C" void kernel_launch(void* const* d_in, const int* in_sizes, int n_in,
                              void* d_out, int out_size, void* d_ws, size_t ws_size,
                              hipStream_t stream) {
  const float* patch  = (const float*)d_in[0];
  const float* conv_w = (const float*)d_in[1];
  const float* conv_b = (const float*)d_in[2];
  const float* fc_w   = (const float*)d_in[3];
  const float* fc_b   = (const float*)d_in[4];
  const float* wmax   = (const float*)d_in[5];
  const float* went   = (const float*)d_in[6];
  const float* wgap   = (const float*)d_in[7];
  const float* thr    = (const float*)d_in[8];
  const int*   epoch  = (const int*)d_in[10];
  float* outp = (float*)d_out;
  _Float16* Bw = (_Float16*)d_ws;                 // 2*21*64*64 B = 172,032 B of ws

  int N = in_sizes[0] / 4352;                     // 16384 samples
  prep_weights<<<336, 256, 0, stream>>>(conv_w, Bw);
  router_main<<<N / 2, 256, 0, stream>>>(patch, conv_b, Bw, fc_w, fc_b,
                                         wmax, went, wgap, thr, epoch, outp);
}